// Round 1
// baseline (61.284 us; speedup 1.0000x reference)
//
#include <hip/hip_runtime.h>

// Spline1DInterpolant: out[q] = sum_i c[i] * u(|s_q - (i+1)|), s_q = (x_q - a)/h + 2,
// h = (b - a)/n, u = cubic B-spline with support |t| <= 2.
//
// For x in [a,b], s in [2, n+2) and f = s - floor(s) in [0,1), so exactly 4 taps
// contribute with CLOSED-FORM weights (no abs/compare/select per tap):
//   c[i0+0] : (1-f)^3                (outer piece, t = 1+f)
//   c[i0+1] : 4 - 6 f^2 + 3 f^3     (inner piece, t = f)
//   c[i0+2] : 4 - 6 g^2 + 3 g^3     (inner piece, t = 1-f, g = 1-f)
//   c[i0+3] : f^3                    (outer piece, t = 2-f)
// with i0 = floor(s) - 2 (0-based). Weights are C^2-continuous across integer s,
// so ULP-level boundary shifts vs the reference are harmless (absmax tol 0.0625).
//
// Tiny-kernel regime: total real traffic ~144 KB; the job is minimizing waves,
// VMEM issue slots, and dependent-latency chain. 4 queries/thread via float4,
// 64 blocks x 64 threads = 64 waves total.

__global__ __launch_bounds__(64) void spline1d_kernel(
    const float* __restrict__ x,
    const float* __restrict__ a,
    const float* __restrict__ b,
    const float* __restrict__ n,
    const float* __restrict__ c,
    float* __restrict__ out,
    int B, int C)
{
    const int tid  = blockIdx.x * blockDim.x + threadIdx.x;
    const int base = tid * 4;
    if (base >= B) return;

    const float av    = a[0];
    const float h     = (b[0] - av) / n[0];
    const float inv_h = 1.0f / h;

    if (base + 3 < B) {
        // fast path: vector load of 4 queries (x is [B,1] contiguous)
        const float4 xv = *reinterpret_cast<const float4*>(x + base);
        const float xs[4] = {xv.x, xv.y, xv.z, xv.w};

        float res[4];
#pragma unroll
        for (int q = 0; q < 4; ++q) {
            const float s  = (xs[q] - av) * inv_h + 2.0f;
            const float j  = floorf(s);
            const float f  = s - j;
            int i0 = (int)j - 2;
            i0 = min(max(i0, 0), C - 4);   // never triggers for x in [a,b]; safety only

            const float f2 = f * f,  f3 = f2 * f;
            const float g  = 1.0f - f;
            const float g2 = g * g,  g3 = g2 * g;

            const float w0 = g3;
            const float w1 = 4.0f - 6.0f * f2 + 3.0f * f3;
            const float w2 = 4.0f - 6.0f * g2 + 3.0f * g3;
            const float w3 = f3;

            // 4 independent dword gathers; all 16 (across q) go in flight together
            res[q] = c[i0] * w0 + c[i0 + 1] * w1 + c[i0 + 2] * w2 + c[i0 + 3] * w3;
        }
        *reinterpret_cast<float4*>(out + base) =
            make_float4(res[0], res[1], res[2], res[3]);
    } else {
        // tail (unused for B % 4 == 0, kept for robustness)
        for (int q = base; q < B; ++q) {
            const float s  = (x[q] - av) * inv_h + 2.0f;
            const float j  = floorf(s);
            const float f  = s - j;
            int i0 = (int)j - 2;
            i0 = min(max(i0, 0), C - 4);
            const float f2 = f * f,  f3 = f2 * f;
            const float g  = 1.0f - f;
            const float g2 = g * g,  g3 = g2 * g;
            out[q] = c[i0] * g3
                   + c[i0 + 1] * (4.0f - 6.0f * f2 + 3.0f * f3)
                   + c[i0 + 2] * (4.0f - 6.0f * g2 + 3.0f * g3)
                   + c[i0 + 3] * f3;
        }
    }
}

extern "C" void kernel_launch(void* const* d_in, const int* in_sizes, int n_in,
                              void* d_out, int out_size, void* d_ws, size_t ws_size,
                              hipStream_t stream) {
    const float* x = (const float*)d_in[0];  // [B,1] -> B floats
    const float* a = (const float*)d_in[1];  // [1]
    const float* b = (const float*)d_in[2];  // [1]
    const float* n = (const float*)d_in[3];  // [1]
    const float* c = (const float*)d_in[4];  // [C]
    float* out = (float*)d_out;              // [B]

    const int B = in_sizes[0];
    const int C = in_sizes[4];

    const int block = 64;
    const int threads_needed = (B + 3) / 4;           // 4 queries per thread
    const int grid = (threads_needed + block - 1) / block;  // 64 blocks for B=16384
    spline1d_kernel<<<grid, block, 0, stream>>>(x, a, b, n, c, out, B, C);
}